// Round 7
// baseline (544.123 us; speedup 1.0000x reference)
//
#include <hip/hip_runtime.h>
#include <hip/hip_bf16.h>

// Problem constants
#define N_TOKENS 8192
#define D_IN     2048
#define HIDDEN   2048
#define N_EXP    8
#define CAP      N_TOKENS       // worst-case tokens per expert (top-2)
#define GATE_BLOCKS 2048        // 4 tokens per block, 1 token per WAVE
#define TPOSE_BLOCKS (N_EXP * 32 * 32)  // 8192 (64x64 tiles)

typedef __bf16 bf16x8 __attribute__((ext_vector_type(8)));
typedef float  f32x4  __attribute__((ext_vector_type(4)));

// Workspace layout (bytes):
//   [0, 1024)              cnt[8*32]  (one counter per 128B line; zeroed per launch)
//   [4096, +8*CAP*4)       bucket_tok (token | slot<<13; slot0 = top1 expert)
//   [266240, +8*CAP*4)     bucket_w
//   [1<<20, +N*D*2)        x_bf16
//   [34603008, +E*D*H*2)   We_t  (bf16, [e][h][d])
//   [101711872, +N*H*4)    p1    (slot-1 partial outputs, f32) -- only if ws fits
#define OFF_CNT   0
#define OFF_TOK   4096
#define OFF_W     266240
#define OFF_XBF   1048576
#define OFF_WET   34603008
#define OFF_P1    101711872ull
#define WS_NEED   (OFF_P1 + (size_t)N_TOKENS * HIDDEN * 4)

__device__ __forceinline__ unsigned short f2bf(float f) {
  unsigned int u = __builtin_bit_cast(unsigned int, f);
  u += 0x7fffu + ((u >> 16) & 1u);   // RNE
  return (unsigned short)(u >> 16);
}

__device__ __forceinline__ void g2l16(const void* g, void* l) {
  // async global->LDS, 16B/lane; LDS dest is wave-uniform base + lane*16
  __builtin_amdgcn_global_load_lds(
      (__attribute__((address_space(1))) void*)g,
      (__attribute__((address_space(3))) void*)l, 16, 0, 0);
}

// ---------------------------------------------------------------------------
// We [e][d][h] f32 -> We_t [e][h][d] bf16   (split from fused prep for
// per-kernel rocprof visibility; round-7)
// ---------------------------------------------------------------------------
__global__ __launch_bounds__(256) void tpose_kernel(
    const float* __restrict__ We, unsigned short* __restrict__ wet)
{
  __shared__ float tile[64][68];
  const int tid = threadIdx.x;
  const int id  = blockIdx.x;
  const int e   = id >> 10;
  const int rem = id & 1023;
  const int d0  = (rem >> 5) << 6;
  const int h0  = (rem & 31) << 6;
  const int r   = tid >> 2;     // 0..63
  const int g   = tid & 3;      // 0..3

  const float* src = We + ((size_t)e * D_IN + d0 + r) * HIDDEN + h0 + g * 16;
#pragma unroll
  for (int i = 0; i < 4; ++i)
    *(float4*)&tile[r][g * 16 + i * 4] = *(const float4*)(src + i * 4);
  __syncthreads();

  union { unsigned short s[16]; uint4 q[2]; } u;
#pragma unroll
  for (int i = 0; i < 16; ++i) u.s[i] = f2bf(tile[g * 16 + i][r]);
  uint4* dst = (uint4*)(wet + ((size_t)e * HIDDEN + h0 + r) * D_IN + d0 + g * 16);
  dst[0] = u.q[0];
  dst[1] = u.q[1];
}

// ---------------------------------------------------------------------------
// Gating + x fp32->bf16, 1 token/wave, SINGLE x pass (round-7: logits are
// computed from the same float4 registers used for the bf16 conversion;
// x read once instead of twice).
// ---------------------------------------------------------------------------
struct GateSM {
  int   lcnt[8];
  int   base[8];
  int   ltok[8][8];      // <=4 tokens x 2 slots per block
  float lw[8][8];
};

__global__ __launch_bounds__(256) void gate_kernel(
    const float* __restrict__ x, const float* __restrict__ Wg,
    const float* __restrict__ bg, unsigned short* __restrict__ xbf,
    int* __restrict__ cnt, int* __restrict__ btok, float* __restrict__ bw)
{
  __shared__ GateSM sm;
  const int tid  = threadIdx.x;
  const int lane = tid & 63;
  const int wid  = tid >> 6;
  if (tid < 8) sm.lcnt[tid] = 0;
  __syncthreads();

  const int n = blockIdx.x * 4 + wid;
  const float* xr = x + (size_t)n * D_IN;
  unsigned short* xbr = xbf + (size_t)n * D_IN;

  float acc[8];
#pragma unroll
  for (int e = 0; e < 8; ++e) acc[e] = 0.f;

#pragma unroll
  for (int c = 0; c < 8; ++c) {
    const int d = c * 256 + lane * 4;
    const float4 xv = *(const float4*)(xr + d);
    // bf16 convert + store (coalesced, 8B/lane)
    uint2 pk;
    pk.x = (unsigned int)f2bf(xv.x) | ((unsigned int)f2bf(xv.y) << 16);
    pk.y = (unsigned int)f2bf(xv.z) | ((unsigned int)f2bf(xv.w) << 16);
    *(uint2*)(xbr + d) = pk;
    // logits from the same registers: rows d..d+3 of Wg (L1/L2-resident)
    const float xs[4] = {xv.x, xv.y, xv.z, xv.w};
#pragma unroll
    for (int j = 0; j < 4; ++j) {
      const float4 g0 = *(const float4*)(Wg + (size_t)(d + j) * 8);
      const float4 g1 = *(const float4*)(Wg + (size_t)(d + j) * 8 + 4);
      acc[0] += xs[j] * g0.x; acc[1] += xs[j] * g0.y;
      acc[2] += xs[j] * g0.z; acc[3] += xs[j] * g0.w;
      acc[4] += xs[j] * g1.x; acc[5] += xs[j] * g1.y;
      acc[6] += xs[j] * g1.z; acc[7] += xs[j] * g1.w;
    }
  }

#pragma unroll
  for (int e = 0; e < 8; ++e) {
    float v = acc[e];
    v += __shfl_down(v, 32); v += __shfl_down(v, 16); v += __shfl_down(v, 8);
    v += __shfl_down(v, 4);  v += __shfl_down(v, 2);  v += __shfl_down(v, 1);
    acc[e] = v;
  }

  if (lane == 0) {
    float lg[8], p[8];
    float mx = -1e30f;
#pragma unroll
    for (int e = 0; e < 8; ++e) { lg[e] = acc[e] + bg[e]; mx = fmaxf(mx, lg[e]); }
    float s = 0.f;
#pragma unroll
    for (int e = 0; e < 8; ++e) { p[e] = expf(lg[e] - mx); s += p[e]; }
    const float inv = 1.f / s;
    int e1 = 0;
#pragma unroll
    for (int e = 1; e < 8; ++e) if (lg[e] > lg[e1]) e1 = e;
    int e2 = (e1 == 0) ? 1 : 0;
#pragma unroll
    for (int e = 0; e < 8; ++e) if (e != e1 && lg[e] > lg[e2]) e2 = e;

    // slot bit: 0 = token's top-1 expert, 1 = top-2
    const int s1 = atomicAdd(&sm.lcnt[e1], 1);
    sm.ltok[e1][s1] = n;              sm.lw[e1][s1] = p[e1] * inv;
    const int s2 = atomicAdd(&sm.lcnt[e2], 1);
    sm.ltok[e2][s2] = n | (1 << 13);  sm.lw[e2][s2] = p[e2] * inv;
  }
  __syncthreads();

  // one global atomic per expert per block (counters on separate 128B lines)
  if (tid < 8) sm.base[tid] = atomicAdd(&cnt[tid * 32], sm.lcnt[tid]);
  __syncthreads();

  const int e = tid >> 5, i = tid & 31;
  if (i < sm.lcnt[e]) {
    const int o = e * CAP + sm.base[e] + i;
    btok[o] = sm.ltok[e][i];
    bw[o]   = sm.lw[e][i];
  }
}

// ---------------------------------------------------------------------------
// Grouped GEMM over expert buckets (128x128 tile, BK=64, bf16 MFMA)
// Round-7 delta: catalog-minimum 2-phase DOUBLE-BUFFERED pipeline (T3-min):
//   prologue: STAGE(buf0, t=0); __syncthreads();
//   loop t:   STAGE(buf^1, t+1) issued FIRST; frag-reads+MFMA from buf;
//             ONE __syncthreads per tile (drains vmcnt+lgkm); swap.
// Stage latency hides under current tile's ds_read+MFMA + cross-block TLP
// (vs round-0/5: stage -> immediate vmcnt(0) drain -> 2 barriers/tile).
// LDS 64 KB -> 2 blocks/CU. Kept from r5 (verified): T1 XCD swizzle,
// XOR LDS swizzle (0 bank conflicts), SLOTTED no-atomic epilogue.
// ---------------------------------------------------------------------------
template <int SLOTTED>
__global__ __launch_bounds__(256, 2) void moe_gemm(
    const unsigned short* __restrict__ xbf, const unsigned short* __restrict__ wet,
    const float* __restrict__ be, const int* __restrict__ cnt,
    const int* __restrict__ btok, const float* __restrict__ bw,
    float* __restrict__ out, float* __restrict__ p1)
{
  // XCD-aware swizzle: flat dispatch id -> (expert = XCD, h outer, m inner)
  const int flat = blockIdx.x + (blockIdx.y << 4) + (blockIdx.z << 10); // 0..8191
  const int swz  = ((flat & 7) << 10) + (flat >> 3);
  const int e    = swz >> 10;
  const int h0   = ((swz >> 6) & 15) << 7;
  const int m0   = (swz & 63) << 7;

  const int M = cnt[e * 32];
  if (m0 >= M) return;

  __shared__ __align__(16) unsigned short As[2][128 * 64];
  __shared__ __align__(16) unsigned short Bs[2][128 * 64];

  const int tid  = threadIdx.x;
  const int wid  = tid >> 6;
  const int lane = tid & 63;
  const int wm   = wid >> 1;   // 0..1
  const int wn   = wid & 1;    // 0..1

  const int* etok = btok + e * CAP;
  const float* ew = bw + e * CAP;

  // swizzled per-lane source column: data for k-chunk (c ^ localrow) goes at lane pos c
  const int kcs = (((lane & 7) ^ (lane >> 3)) * 8);

  size_t asrc[4], bsrc[4];
#pragma unroll
  for (int j = 0; j < 4; ++j) {
    const int c = wid * 4 + j;               // chunk 0..15 (8 rows each)
    const int r = c * 8 + (lane >> 3);       // row within 128-tile
    int ar = m0 + r;
    if (ar >= M) ar = m0;                    // clamp (discarded in epilogue)
    const int tok = etok[ar] & 8191;         // strip slot bit
    asrc[j] = (size_t)tok * D_IN + kcs;
    bsrc[j] = ((size_t)e * HIDDEN + h0 + r) * D_IN + kcs;
  }

  f32x4 acc[4][4];
#pragma unroll
  for (int i = 0; i < 4; ++i)
#pragma unroll
    for (int j = 0; j < 4; ++j) acc[i][j] = (f32x4){0.f, 0.f, 0.f, 0.f};

#define STAGE(b_, k_) {                                                        \
    _Pragma("unroll")                                                          \
    for (int j = 0; j < 4; ++j)                                                \
      g2l16(xbf + asrc[j] + (k_), &As[b_][(wid * 4 + j) * 512]);               \
    _Pragma("unroll")                                                          \
    for (int j = 0; j < 4; ++j)                                                \
      g2l16(wet + bsrc[j] + (k_), &Bs[b_][(wid * 4 + j) * 512]); }

  // prologue: stage K-tile 0 into buf0
  STAGE(0, 0);
  __syncthreads();

  int cur = 0;
#pragma unroll 1
  for (int t = 0; t < D_IN / 64; ++t) {
    // issue next tile's staging FIRST (latency hides under this tile's compute)
    const int kn = (t + 1) * 64;
    if (kn < D_IN) {
      if (cur) STAGE(0, kn) else STAGE(1, kn);
    }

    const unsigned short* Ab = &As[cur][0];
    const unsigned short* Bb = &Bs[cur][0];
#pragma unroll
    for (int kh = 0; kh < 2; ++kh) {
      bf16x8 af[4], bfr[4];
#pragma unroll
      for (int fm = 0; fm < 4; ++fm) {
        const int row = wm * 64 + fm * 16 + (lane & 15);
        const int kc  = kh * 4 + (lane >> 4);
        af[fm] = __builtin_bit_cast(bf16x8,
            *(const uint4*)(Ab + row * 64 + ((kc ^ (row & 7)) * 8)));
      }
#pragma unroll
      for (int fn = 0; fn < 4; ++fn) {
        const int row = wn * 64 + fn * 16 + (lane & 15);
        const int kc  = kh * 4 + (lane >> 4);
        bfr[fn] = __builtin_bit_cast(bf16x8,
            *(const uint4*)(Bb + row * 64 + ((kc ^ (row & 7)) * 8)));
      }
#pragma unroll
      for (int fm = 0; fm < 4; ++fm)
#pragma unroll
        for (int fn = 0; fn < 4; ++fn)
          acc[fm][fn] = __builtin_amdgcn_mfma_f32_16x16x32_bf16(
              af[fm], bfr[fn], acc[fm][fn], 0, 0, 0);
    }

    // ONE barrier per tile: drains this wave's stage loads (vmcnt) and
    // signals all waves' frag reads of buf[cur] complete -> safe to swap.
    __syncthreads();
    cur ^= 1;
  }
#undef STAGE

  // Epilogue: val = w * (acc + be[e][h]); C layout: col=lane&15, row=(lane>>4)*4+reg
  float bias[4];
#pragma unroll
  for (int fn = 0; fn < 4; ++fn)
    bias[fn] = be[e * HIDDEN + h0 + wn * 64 + fn * 16 + (lane & 15)];

#pragma unroll
  for (int fm = 0; fm < 4; ++fm) {
    const int rbase = m0 + wm * 64 + fm * 16 + (lane >> 4) * 4;
#pragma unroll
    for (int reg = 0; reg < 4; ++reg) {
      const int r = rbase + reg;
      if (r < M) {
        const int tv  = etok[r];
        const int tok = tv & 8191;
        const float w = ew[r];
        if (SLOTTED) {
          // plain store: slot0 -> out, slot1 -> p1 (no RMW, no atomics)
          float* dst = ((tv >> 13) ? p1 : out) +
                       (size_t)tok * HIDDEN + h0 + wn * 64 + (lane & 15);
#pragma unroll
          for (int fn = 0; fn < 4; ++fn)
            dst[fn * 16] = w * (acc[fm][fn][reg] + bias[fn]);
        } else {
          float* orow = out + (size_t)tok * HIDDEN + h0 + wn * 64 + (lane & 15);
#pragma unroll
          for (int fn = 0; fn < 4; ++fn)
            atomicAdd(orow + fn * 16, w * (acc[fm][fn][reg] + bias[fn]));
        }
      }
    }
  }
}

// ---------------------------------------------------------------------------
// out += p1 (both fully written by the GEMM; no zero-init needed anywhere)
// ---------------------------------------------------------------------------
__global__ __launch_bounds__(256) void combine_kernel(
    float* __restrict__ out, const float* __restrict__ p1)
{
  const int stride = gridDim.x * 256;
  for (int i = blockIdx.x * 256 + threadIdx.x;
       i < N_TOKENS * HIDDEN / 4; i += stride) {
    float4 a = ((const float4*)out)[i];
    const float4 b = ((const float4*)p1)[i];
    a.x += b.x; a.y += b.y; a.z += b.z; a.w += b.w;
    ((float4*)out)[i] = a;
  }
}

// ---------------------------------------------------------------------------
extern "C" void kernel_launch(void* const* d_in, const int* in_sizes, int n_in,
                              void* d_out, int out_size, void* d_ws, size_t ws_size,
                              hipStream_t stream) {
  const float* x  = (const float*)d_in[0];
  const float* Wg = (const float*)d_in[1];
  const float* bg = (const float*)d_in[2];
  const float* We = (const float*)d_in[3];
  const float* be = (const float*)d_in[4];
  float* out = (float*)d_out;

  char* ws = (char*)d_ws;
  int*            cnt  = (int*)(ws + OFF_CNT);
  int*            btok = (int*)(ws + OFF_TOK);
  float*          bw   = (float*)(ws + OFF_W);
  unsigned short* xbf  = (unsigned short*)(ws + OFF_XBF);
  unsigned short* wet  = (unsigned short*)(ws + OFF_WET);
  float*          p1   = (float*)(ws + OFF_P1);

  const bool slotted = (ws_size >= WS_NEED);

  hipMemsetAsync(cnt, 0, 8 * 32 * sizeof(int), stream);
  if (!slotted)
    hipMemsetAsync(d_out, 0, (size_t)out_size * sizeof(float), stream);

  tpose_kernel<<<TPOSE_BLOCKS, 256, 0, stream>>>(We, wet);
  gate_kernel<<<GATE_BLOCKS, 256, 0, stream>>>(x, Wg, bg, xbf, cnt, btok, bw);

  if (slotted) {
    moe_gemm<1><<<dim3(HIDDEN / 128, N_TOKENS / 128, N_EXP), 256, 0, stream>>>(
        xbf, wet, be, cnt, btok, bw, out, p1);
    combine_kernel<<<2048, 256, 0, stream>>>(out, p1);
  } else {
    moe_gemm<0><<<dim3(HIDDEN / 128, N_TOKENS / 128, N_EXP), 256, 0, stream>>>(
        xbf, wet, be, cnt, btok, bw, out, p1);
  }
}